// Round 2
// baseline (707.838 us; speedup 1.0000x reference)
//
#include <hip/hip_runtime.h>
#include <cstddef>

#define T_DIM 2048
#define B_DIM 64
#define V_DIM 128
#define LMAX  128
#define ROW   132              // em row stride in floats (129 used, padded)
#define INV_LN2 1.44269504088896340736f
#define LN2F    0.69314718055994530942f
#define NEG2   -1.0e30f        // 'log-zero' in log2 domain
#define DEPTH 16

__device__ __forceinline__ float exp2_fast(float x){ return __builtin_amdgcn_exp2f(x); }
__device__ __forceinline__ float log2_fast(float x){ return __builtin_amdgcn_logf(x); }

// log2-domain logaddexp: 2 transcendentals
__device__ __forceinline__ float lae2(float a, float b){
  float m = fmaxf(a, b);
  float d = fabsf(a - b);
  return m + log2_fast(1.0f + exp2_fast(-d));
}
// 3-way: 4 transcendentals
__device__ __forceinline__ float lae3(float a, float b, float c){
  float m = fmaxf(fmaxf(a, b), c);
  return m + log2_fast(exp2_fast(a - m) + exp2_fast(b - m) + exp2_fast(c - m));
}

// ---- Kernel 1: fused LSE + emission-stream build --------------------------
// one wave per (t,b) row of acts; writes em[b][t][j] = log2 p_j, blank at j=128
__global__ __launch_bounds__(256) void em_kernel(const float* __restrict__ acts,
                                                 const int* __restrict__ labels,
                                                 const int* __restrict__ label_lens,
                                                 float* __restrict__ em){
  const int wid  = threadIdx.x >> 6;
  const int lane = threadIdx.x & 63;
  const int row  = blockIdx.x * 4 + wid;          // row = t*B + b
  const int t = row >> 6;
  const int b = row & (B_DIM - 1);

  __shared__ float sh[4][V_DIM];

  const float2 v = ((const float2*)(acts + (size_t)row * V_DIM))[lane];
  float m = fmaxf(v.x, v.y);
  #pragma unroll
  for (int o = 32; o; o >>= 1) m = fmaxf(m, __shfl_xor(m, o, 64));
  float s = exp2_fast((v.x - m) * INV_LN2) + exp2_fast((v.y - m) * INV_LN2);
  #pragma unroll
  for (int o = 32; o; o >>= 1) s += __shfl_xor(s, o, 64);
  const float d2 = fmaf(m, INV_LN2, log2_fast(s));     // log2 of softmax denom

  sh[wid][2 * lane]     = v.x;
  sh[wid][2 * lane + 1] = v.y;

  // label offset for this b
  int masked = (lane < b) ? label_lens[lane] : 0;
  int off = masked;
  #pragma unroll
  for (int o = 1; o < 64; o <<= 1) off += __shfl_xor(off, o, 64);
  const int L = label_lens[b];

  __syncthreads();

  const int j0 = 2 * lane, j1 = 2 * lane + 1;
  const int lab0 = (j0 < L) ? labels[off + j0] : 0;
  const int lab1 = (j1 < L) ? labels[off + j1] : 0;
  float e0 = fmaf(sh[wid][lab0], INV_LN2, -d2);
  float e1 = fmaf(sh[wid][lab1], INV_LN2, -d2);

  float* er = em + ((size_t)b * T_DIM + t) * ROW;
  ((float2*)er)[lane] = make_float2(e0, e1);
  if (lane == 0) er[2 * LMAX] = fmaf(sh[wid][0], INV_LN2, -d2);   // blank
}

// ---- Kernel 2: per-batch serial CTC alpha recursion (1 wave / b) ----------
__global__ __launch_bounds__(64) void ctc_kernel(const float* __restrict__ em,
                                                 const int* __restrict__ labels,
                                                 const int* __restrict__ act_lens,
                                                 const int* __restrict__ label_lens,
                                                 float* __restrict__ costs){
  const int b = blockIdx.x, tid = threadIdx.x;
  const int L = label_lens[b];
  int alen = act_lens[b]; if (alen > T_DIM) alen = T_DIM;

  int masked = (tid < b) ? label_lens[tid] : 0;
  int off = masked;
  #pragma unroll
  for (int o = 1; o < 64; o <<= 1) off += __shfl_xor(off, o, 64);

  const int j0 = 2 * tid, j1 = 2 * tid + 1, jm1 = 2 * tid - 1;
  const int lab0  = (j0 < L) ? labels[off + j0] : 0;
  const int lab1  = (j1 < L) ? labels[off + j1] : 0;
  const int labm1 = (tid == 0) ? -1 : ((jm1 < L) ? labels[off + jm1] : 0);
  const bool skip1 = (lab0 != 0) && (lab0 != labm1);
  const bool skip3 = (lab1 != 0) && (lab1 != lab0);

  float a0 = (tid == 0) ? 0.0f : NEG2;
  float a1 = NEG2, a2 = NEG2, a3 = NEG2, a4 = NEG2;
  float a3L = NEG2;                      // alpha[4tid-1] from left neighbor (pipelined)

  const float* em_b = em + (size_t)b * T_DIM * ROW;

  float2 pf[DEPTH]; float pb[DEPTH];
  #pragma unroll
  for (int k = 0; k < DEPTH; ++k){
    pf[k] = ((const float2*)(em_b + (size_t)k * ROW))[tid];
    pb[k] = em_b[(size_t)k * ROW + 2 * LMAX];
  }

  for (int t0 = 0; t0 < alen; t0 += DEPTH){
    #pragma unroll
    for (int k = 0; k < DEPTH; ++k){
      const int t = t0 + k;
      if (t >= alen) break;              // wave-uniform
      const float e0 = pf[k].x, e1 = pf[k].y, eb = pb[k];
      const float c1 = skip1 ? a3L : NEG2;
      const float c3 = skip3 ? a1  : NEG2;
      const float n0 = eb + lae2(a0, a3L);
      const float n1 = e0 + lae3(a1, a0, c1);
      const float n2 = eb + lae2(a2, a1);
      const float n3 = e1 + lae3(a3, a2, c3);
      const float n4 = eb + lae2(a4, a3);
      float nl = __shfl_up(n3, 1, 64);   // issued early; latency overlaps next step
      a3L = (tid == 0) ? NEG2 : nl;
      a0 = n0; a1 = n1; a2 = n2; a3 = n3; a4 = n4;
      int tn = t + DEPTH; if (tn > T_DIM - 1) tn = T_DIM - 1;
      pf[k] = ((const float2*)(em_b + (size_t)tn * ROW))[tid];
      pb[k] = em_b[(size_t)tn * ROW + 2 * LMAX];
    }
  }

  __shared__ float A[260];
  A[4 * tid] = a0; A[4 * tid + 1] = a1; A[4 * tid + 2] = a2; A[4 * tid + 3] = a3;
  if (tid == 63) A[256] = a4;
  __syncthreads();
  if (tid == 0){
    const int sL = 2 * L;
    costs[b] = -LN2F * lae2(A[sL], A[sL - 1]);
  }
}

// ---- Kernel 3: deterministic sum ------------------------------------------
__global__ __launch_bounds__(64) void sum_kernel(const float* __restrict__ costs,
                                                 float* __restrict__ out){
  float v = costs[threadIdx.x];
  #pragma unroll
  for (int o = 32; o; o >>= 1) v += __shfl_xor(v, o, 64);
  if (threadIdx.x == 0) out[0] = v;
}

// ---- Fallback path (round-1, in case ws is too small) ---------------------
__global__ __launch_bounds__(256) void lse_kernel(const float* __restrict__ acts,
                                                  float* __restrict__ denom){
  int row  = (blockIdx.x * 256 + threadIdx.x) >> 6;
  int lane = threadIdx.x & 63;
  if (row >= T_DIM * B_DIM) return;
  const float2 v = ((const float2*)(acts + (size_t)row * V_DIM))[lane];
  float m = fmaxf(v.x, v.y);
  #pragma unroll
  for (int o = 32; o; o >>= 1) m = fmaxf(m, __shfl_xor(m, o, 64));
  float s = exp2_fast((v.x - m) * INV_LN2) + exp2_fast((v.y - m) * INV_LN2);
  #pragma unroll
  for (int o = 32; o; o >>= 1) s += __shfl_xor(s, o, 64);
  if (lane == 0) denom[row] = fmaf(m, INV_LN2, log2_fast(s));
}

__global__ __launch_bounds__(64) void ctc_gather_kernel(
    const float* __restrict__ acts, const int* __restrict__ labels,
    const int* __restrict__ act_lens, const int* __restrict__ label_lens,
    const float* __restrict__ denom, float* __restrict__ costs){
  const int b = blockIdx.x, tid = threadIdx.x;
  const int L = label_lens[b];
  int alen = act_lens[b]; if (alen > T_DIM) alen = T_DIM;
  int masked = (tid < b) ? label_lens[tid] : 0;
  int off = masked;
  #pragma unroll
  for (int o = 1; o < 64; o <<= 1) off += __shfl_xor(off, o, 64);
  const int j0 = 2 * tid, j1 = 2 * tid + 1, jm1 = 2 * tid - 1;
  const int lab0  = (j0 < L) ? labels[off + j0] : 0;
  const int lab1  = (j1 < L) ? labels[off + j1] : 0;
  const int labm1 = (tid == 0) ? -1 : ((jm1 < L) ? labels[off + jm1] : 0);
  const bool skip1 = (lab0 != 0) && (lab0 != labm1);
  const bool skip3 = (lab1 != 0) && (lab1 != lab0);
  float a0 = (tid == 0) ? 0.0f : NEG2;
  float a1 = NEG2, a2 = NEG2, a3 = NEG2, a4 = NEG2, a3L = NEG2;
  const float* actsB = acts + (size_t)b * V_DIM;
  for (int t = 0; t < alen; ++t){
    const float* base = actsB + (size_t)t * (B_DIM * V_DIM);
    const float d  = denom[t * B_DIM + b];
    const float eb = fmaf(base[0],    INV_LN2, -d);
    const float e0 = fmaf(base[lab0], INV_LN2, -d);
    const float e1 = fmaf(base[lab1], INV_LN2, -d);
    const float c1 = skip1 ? a3L : NEG2;
    const float c3 = skip3 ? a1  : NEG2;
    const float n0 = eb + lae2(a0, a3L);
    const float n1 = e0 + lae3(a1, a0, c1);
    const float n2 = eb + lae2(a2, a1);
    const float n3 = e1 + lae3(a3, a2, c3);
    const float n4 = eb + lae2(a4, a3);
    float nl = __shfl_up(n3, 1, 64);
    a3L = (tid == 0) ? NEG2 : nl;
    a0 = n0; a1 = n1; a2 = n2; a3 = n3; a4 = n4;
  }
  __shared__ float A[260];
  A[4 * tid] = a0; A[4 * tid + 1] = a1; A[4 * tid + 2] = a2; A[4 * tid + 3] = a3;
  if (tid == 63) A[256] = a4;
  __syncthreads();
  if (tid == 0){
    const int sL = 2 * L;
    costs[b] = -LN2F * lae2(A[sL], A[sL - 1]);
  }
}

extern "C" void kernel_launch(void* const* d_in, const int* in_sizes, int n_in,
                              void* d_out, int out_size, void* d_ws, size_t ws_size,
                              hipStream_t stream){
  const float* acts       = (const float*)d_in[0];
  const int*   labels     = (const int*)d_in[1];
  const int*   act_lens   = (const int*)d_in[2];
  const int*   label_lens = (const int*)d_in[3];
  float* out = (float*)d_out;

  const size_t em_floats = (size_t)B_DIM * T_DIM * ROW;
  const size_t need = (em_floats + 64) * sizeof(float);

  if (ws_size >= need){
    float* em    = (float*)d_ws;
    float* costs = em + em_floats;
    em_kernel<<<(T_DIM * B_DIM) / 4, 256, 0, stream>>>(acts, labels, label_lens, em);
    ctc_kernel<<<B_DIM, 64, 0, stream>>>(em, labels, act_lens, label_lens, costs);
    sum_kernel<<<1, 64, 0, stream>>>(costs, out);
  } else {
    float* denom = (float*)d_ws;                    // T*B floats
    float* costs = denom + (size_t)T_DIM * B_DIM;
    lse_kernel<<<(T_DIM * B_DIM) / 4, 256, 0, stream>>>(acts, denom);
    ctc_gather_kernel<<<B_DIM, 64, 0, stream>>>(acts, labels, act_lens, label_lens, denom, costs);
    sum_kernel<<<1, 64, 0, stream>>>(costs, out);
  }
}

// Round 3
// 225.945 us; speedup vs baseline: 3.1328x; 3.1328x over previous
//
#include <hip/hip_runtime.h>
#include <cstddef>

#define T_DIM 2048
#define B_DIM 64
#define V_DIM 128
#define LMAX  128
#define ROWF  132                      // floats per em row (129 used; blank at [128])
#define CHUNK 16                       // time steps per staged chunk
#define CHUNK_FLOATS (CHUNK * ROWF)    // 2112
#define CHUNK_BYTES  (CHUNK_FLOATS*4)  // 8448 = 8*1024 + 256
#define NCHUNK (T_DIM / CHUNK)         // 128
#define INV_LN2 1.44269504088896340736f
#define LN2F    0.69314718055994530942f
#define NEG2   -1.0e30f

__device__ __forceinline__ float exp2_fast(float x){ return __builtin_amdgcn_exp2f(x); }
__device__ __forceinline__ float log2_fast(float x){ return __builtin_amdgcn_logf(x); }

__device__ __forceinline__ float lae2_log2(float a, float b){
  float m = fmaxf(a, b);
  float d = fabsf(a - b);
  return m + log2_fast(1.0f + exp2_fast(-d));
}
__device__ __forceinline__ float lae3_log2(float a, float b, float c){
  float m = fmaxf(fmaxf(a, b), c);
  return m + log2_fast(exp2_fast(a - m) + exp2_fast(b - m) + exp2_fast(c - m));
}

// async global->LDS: 8448 bytes = 8 x (64 lanes x 16B) + 1 x (64 lanes x 4B)
__device__ __forceinline__ void stage_chunk(const char* gsrc, float* ldst){
  const int lane = threadIdx.x & 63;
  #pragma unroll
  for (int i = 0; i < 8; ++i){
    __builtin_amdgcn_global_load_lds(
      (const __attribute__((address_space(1))) unsigned int*)(gsrc + i*1024 + lane*16),
      (__attribute__((address_space(3))) unsigned int*)((char*)ldst + i*1024),
      16, 0, 0);
  }
  __builtin_amdgcn_global_load_lds(
      (const __attribute__((address_space(1))) unsigned int*)(gsrc + 8192 + lane*4),
      (__attribute__((address_space(3))) unsigned int*)((char*)ldst + 8192),
      4, 0, 0);
}

// ---- Kernel 1: fused softmax + per-b emission-prob stream (linear domain) ----
__global__ __launch_bounds__(256) void em_kernel(const float* __restrict__ acts,
                                                 const int* __restrict__ labels,
                                                 const int* __restrict__ label_lens,
                                                 float* __restrict__ em){
  const int wid  = threadIdx.x >> 6;
  const int lane = threadIdx.x & 63;
  const int row  = blockIdx.x * 4 + wid;          // row = t*B + b
  const int t = row >> 6;
  const int b = row & (B_DIM - 1);

  __shared__ float sh[4][V_DIM];

  const float2 v = ((const float2*)(acts + (size_t)row * V_DIM))[lane];
  float m = fmaxf(v.x, v.y);
  #pragma unroll
  for (int o = 32; o; o >>= 1) m = fmaxf(m, __shfl_xor(m, o, 64));
  float s = exp2_fast((v.x - m) * INV_LN2) + exp2_fast((v.y - m) * INV_LN2);
  #pragma unroll
  for (int o = 32; o; o >>= 1) s += __shfl_xor(s, o, 64);
  const float d2 = fmaf(m, INV_LN2, log2_fast(s));     // log2 softmax denom

  sh[wid][2 * lane]     = v.x;
  sh[wid][2 * lane + 1] = v.y;

  int masked = (lane < b) ? label_lens[lane] : 0;
  int off = masked;
  #pragma unroll
  for (int o = 1; o < 64; o <<= 1) off += __shfl_xor(off, o, 64);
  const int L = label_lens[b];

  __syncthreads();

  const int j0 = 2 * lane, j1 = 2 * lane + 1;
  const int lab0 = (j0 < L) ? labels[off + j0] : 0;
  const int lab1 = (j1 < L) ? labels[off + j1] : 0;
  const float p0 = exp2_fast(fmaf(sh[wid][lab0], INV_LN2, -d2));   // linear probs
  const float p1 = exp2_fast(fmaf(sh[wid][lab1], INV_LN2, -d2));

  float* er = em + ((size_t)b * T_DIM + t) * ROWF;
  ((float2*)er)[lane] = make_float2(p0, p1);
  if (lane == 0) er[128] = exp2_fast(fmaf(sh[wid][0], INV_LN2, -d2));  // blank, in-row
}

// ---- Kernel 2: per-batch linear-domain CTC recursion, 1 wave / b -------------
__global__ __launch_bounds__(64) void ctc_lin_kernel(const float* __restrict__ em,
    const int* __restrict__ labels, const int* __restrict__ act_lens,
    const int* __restrict__ label_lens, float* __restrict__ costs)
{
  __shared__ __align__(16) float sbuf[3 * CHUNK_FLOATS];   // 25.3 KB ring
  __shared__ float A[257];
  __shared__ int   KK[64];

  const int b = blockIdx.x, tid = threadIdx.x;
  const int L = label_lens[b];
  int alen = act_lens[b]; if (alen > T_DIM) alen = T_DIM; if (alen < 1) alen = 1;

  int masked = (tid < b) ? label_lens[tid] : 0;
  int off = masked;
  #pragma unroll
  for (int o = 1; o < 64; o <<= 1) off += __shfl_xor(off, o, 64);

  const int j0 = 2*tid, j1 = 2*tid+1, jm1 = 2*tid-1;
  const int lab0  = (j0 < L) ? labels[off + j0] : 0;
  const int lab1  = (j1 < L) ? labels[off + j1] : 0;
  const int labm1 = (tid == 0) ? -1 : ((jm1 < L) ? labels[off + jm1] : 0);
  const bool skip1 = (lab0 != 0) && (lab0 != labm1);
  const bool skip3 = (lab1 != 0) && (lab1 != lab0);

  // linear-domain alpha, per-thread block exponent K: true = a * 2^K
  float a0 = (tid == 0) ? 1.0f : 0.0f;
  float a1 = 0.0f, a2 = 0.0f, a3 = 0.0f, a4 = 0.0f;
  int K = 0;
  float a3L = 0.0f;        // left neighbor's a3 (in left frame)
  float factor0 = 0.0f;    // 2^(KL-K), zeroed on tid 0

  const char* em_b = (const char*)(em + (size_t)b * T_DIM * ROWF);

  stage_chunk(em_b + 0*(size_t)CHUNK_BYTES, sbuf);
  stage_chunk(em_b + 1*(size_t)CHUNK_BYTES, sbuf + CHUNK_FLOATS);
  float* cur = sbuf;
  float* nxt = sbuf + CHUNK_FLOATS;
  float* nn  = sbuf + 2*CHUNK_FLOATS;

  auto boundary = [&](){
    float m = fmaxf(fmaxf(fmaxf(a0, a1), fmaxf(a2, a3)), a4);
    int e; (void)frexpf(m, &e);                 // m==0 -> e=0
    const float sc = ldexpf(1.0f, -e);          // normalize max to [0.5,1)
    a0 *= sc; a1 *= sc; a2 *= sc; a3 *= sc; a4 *= sc;
    K += e;
    const bool dead = (m == 0.0f);
    int KL = __shfl_up(K, 1, 64);
    if (tid == 0) KL = K;
    K = dead ? KL : K;                          // adopt left frame when dead
    const int shift = KL - K;                   // 0 when dead/adopted
    const float f = ldexpf(1.0f, shift);
    factor0 = (tid == 0) ? 0.0f : f;
    a3L = __shfl_up(a3, 1, 64);                 // refresh post-rescale
  };

  auto step = [&](float p0, float p1, float pb){
    const float a3Le = a3L * factor0;
    const float c1 = skip1 ? a3Le : 0.0f;
    const float c3 = skip3 ? a1   : 0.0f;
    const float n0 = pb * (a0 + a3Le);
    const float n1 = p0 * (a1 + a0 + c1);
    const float n2 = pb * (a2 + a1);
    const float n3 = p1 * (a3 + a2 + c3);
    const float n4 = pb * (a4 + a3);
    a3L = __shfl_up(n3, 1, 64);
    a0 = n0; a1 = n1; a2 = n2; a3 = n3; a4 = n4;
  };

  const int nfull = alen >> 4;
  const int rem   = alen & 15;

  for (int c = 0; c < nfull; ++c){
    if (c + 2 < NCHUNK){
      stage_chunk(em_b + (size_t)(c + 2) * CHUNK_BYTES, nn);
      asm volatile("s_waitcnt vmcnt(18)" ::: "memory");   // chunk c ready; 2 in flight
    } else {
      asm volatile("s_waitcnt vmcnt(0)" ::: "memory");
    }
    #pragma unroll
    for (int w = 0; w < 4; ++w){
      float2 P[4]; float PB[4];
      #pragma unroll
      for (int k = 0; k < 4; ++k){
        const float* r = cur + (w*4 + k) * ROWF;
        P[k]  = *(const float2*)(r + 2*tid);
        PB[k] = r[128];
      }
      boundary();
      #pragma unroll
      for (int k = 0; k < 4; ++k) step(P[k].x, P[k].y, PB[k]);
    }
    float* t0 = cur; cur = nxt; nxt = nn; nn = t0;
  }
  if (rem){
    asm volatile("s_waitcnt vmcnt(0)" ::: "memory");
    #pragma unroll
    for (int w = 0; w < 4; ++w){
      float2 P[4]; float PB[4];
      #pragma unroll
      for (int k = 0; k < 4; ++k){
        const float* r = cur + (w*4 + k) * ROWF;
        P[k]  = *(const float2*)(r + 2*tid);
        PB[k] = r[128];
      }
      if (w*4 < rem){
        boundary();
        #pragma unroll
        for (int k = 0; k < 4; ++k){ if (w*4 + k < rem) step(P[k].x, P[k].y, PB[k]); }
      }
    }
  }

  A[4*tid] = a0; A[4*tid+1] = a1; A[4*tid+2] = a2; A[4*tid+3] = a3;
  if (tid == 63) A[256] = a4;
  KK[tid] = K;
  __syncthreads();
  if (tid == 0){
    const int sL = 2 * L;
    int ia = sL >> 2;       if (ia > 63) ia = 63;
    int ib = (sL - 1) >> 2; if (ib > 63) ib = 63;
    const float la = log2_fast(A[sL])     + (float)KK[ia];
    const float lb = log2_fast(A[sL - 1]) + (float)KK[ib];
    costs[b] = -LN2F * lae2_log2(la, lb);
  }
}

// ---- Kernel 3: deterministic sum ------------------------------------------
__global__ __launch_bounds__(64) void sum_kernel(const float* __restrict__ costs,
                                                 float* __restrict__ out){
  float v = costs[threadIdx.x];
  #pragma unroll
  for (int o = 32; o; o >>= 1) v += __shfl_xor(v, o, 64);
  if (threadIdx.x == 0) out[0] = v;
}

// ---- Fallback path (proven round-1, if ws too small) -----------------------
__global__ __launch_bounds__(256) void lse_kernel(const float* __restrict__ acts,
                                                  float* __restrict__ denom){
  int row  = (blockIdx.x * 256 + threadIdx.x) >> 6;
  int lane = threadIdx.x & 63;
  if (row >= T_DIM * B_DIM) return;
  const float2 v = ((const float2*)(acts + (size_t)row * V_DIM))[lane];
  float m = fmaxf(v.x, v.y);
  #pragma unroll
  for (int o = 32; o; o >>= 1) m = fmaxf(m, __shfl_xor(m, o, 64));
  float s = exp2_fast((v.x - m) * INV_LN2) + exp2_fast((v.y - m) * INV_LN2);
  #pragma unroll
  for (int o = 32; o; o >>= 1) s += __shfl_xor(s, o, 64);
  if (lane == 0) denom[row] = fmaf(m, INV_LN2, log2_fast(s));
}

__global__ __launch_bounds__(64) void ctc_gather_kernel(
    const float* __restrict__ acts, const int* __restrict__ labels,
    const int* __restrict__ act_lens, const int* __restrict__ label_lens,
    const float* __restrict__ denom, float* __restrict__ costs){
  const int b = blockIdx.x, tid = threadIdx.x;
  const int L = label_lens[b];
  int alen = act_lens[b]; if (alen > T_DIM) alen = T_DIM;
  int masked = (tid < b) ? label_lens[tid] : 0;
  int off = masked;
  #pragma unroll
  for (int o = 1; o < 64; o <<= 1) off += __shfl_xor(off, o, 64);
  const int j0 = 2*tid, j1 = 2*tid+1, jm1 = 2*tid-1;
  const int lab0  = (j0 < L) ? labels[off + j0] : 0;
  const int lab1  = (j1 < L) ? labels[off + j1] : 0;
  const int labm1 = (tid == 0) ? -1 : ((jm1 < L) ? labels[off + jm1] : 0);
  const bool skip1 = (lab0 != 0) && (lab0 != labm1);
  const bool skip3 = (lab1 != 0) && (lab1 != lab0);
  float a0 = (tid == 0) ? 0.0f : NEG2;
  float a1 = NEG2, a2 = NEG2, a3 = NEG2, a4 = NEG2, a3L = NEG2;
  const float* actsB = acts + (size_t)b * V_DIM;
  for (int t = 0; t < alen; ++t){
    const float* base = actsB + (size_t)t * (B_DIM * V_DIM);
    const float d  = denom[t * B_DIM + b];
    const float eb = fmaf(base[0],    INV_LN2, -d);
    const float e0 = fmaf(base[lab0], INV_LN2, -d);
    const float e1 = fmaf(base[lab1], INV_LN2, -d);
    const float c1 = skip1 ? a3L : NEG2;
    const float c3 = skip3 ? a1  : NEG2;
    const float n0 = eb + lae2_log2(a0, a3L);
    const float n1 = e0 + lae3_log2(a1, a0, c1);
    const float n2 = eb + lae2_log2(a2, a1);
    const float n3 = e1 + lae3_log2(a3, a2, c3);
    const float n4 = eb + lae2_log2(a4, a3);
    float nl = __shfl_up(n3, 1, 64);
    a3L = (tid == 0) ? NEG2 : nl;
    a0 = n0; a1 = n1; a2 = n2; a3 = n3; a4 = n4;
  }
  __shared__ float A[257];
  A[4*tid] = a0; A[4*tid+1] = a1; A[4*tid+2] = a2; A[4*tid+3] = a3;
  if (tid == 63) A[256] = a4;
  __syncthreads();
  if (tid == 0){
    const int sL = 2 * L;
    costs[b] = -LN2F * lae2_log2(A[sL], A[sL - 1]);
  }
}

extern "C" void kernel_launch(void* const* d_in, const int* in_sizes, int n_in,
                              void* d_out, int out_size, void* d_ws, size_t ws_size,
                              hipStream_t stream){
  const float* acts       = (const float*)d_in[0];
  const int*   labels     = (const int*)d_in[1];
  const int*   act_lens   = (const int*)d_in[2];
  const int*   label_lens = (const int*)d_in[3];
  float* out = (float*)d_out;

  const size_t em_floats = (size_t)B_DIM * T_DIM * ROWF;
  const size_t need = (em_floats + 64) * sizeof(float);

  if (ws_size >= need){
    float* em    = (float*)d_ws;
    float* costs = em + em_floats;
    em_kernel<<<(T_DIM * B_DIM) / 4, 256, 0, stream>>>(acts, labels, label_lens, em);
    ctc_lin_kernel<<<B_DIM, 64, 0, stream>>>(em, labels, act_lens, label_lens, costs);
    sum_kernel<<<1, 64, 0, stream>>>(costs, out);
  } else {
    float* denom = (float*)d_ws;
    float* costs = denom + (size_t)T_DIM * B_DIM;
    lse_kernel<<<(T_DIM * B_DIM) / 4, 256, 0, stream>>>(acts, denom);
    ctc_gather_kernel<<<B_DIM, 64, 0, stream>>>(acts, labels, act_lens, label_lens, denom, costs);
    sum_kernel<<<1, 64, 0, stream>>>(costs, out);
  }
}

// Round 4
// 181.678 us; speedup vs baseline: 3.8961x; 1.2437x over previous
//
#include <hip/hip_runtime.h>
#include <cstddef>

#define T_DIM 2048
#define B_DIM 64
#define V_DIM 128
#define LMAX  128
#define ROWF  132                      // floats per em row (129 used; blank at [128])
#define CHUNK 16                       // time steps per staged chunk
#define CHUNK_FLOATS (CHUNK * ROWF)    // 2112
#define CHUNK_BYTES  (CHUNK_FLOATS*4)  // 8448 = 8*1024 + 256
#define NCHUNK (T_DIM / CHUNK)         // 128
#define INV_LN2 1.44269504088896340736f
#define LN2F    0.69314718055994530942f
#define NEG2   -1.0e30f

__device__ __forceinline__ float exp2_fast(float x){ return __builtin_amdgcn_exp2f(x); }
__device__ __forceinline__ float log2_fast(float x){ return __builtin_amdgcn_logf(x); }

__device__ __forceinline__ float lae2_log2(float a, float b){
  float m = fmaxf(a, b);
  float d = fabsf(a - b);
  return m + log2_fast(1.0f + exp2_fast(-d));
}
__device__ __forceinline__ float lae3_log2(float a, float b, float c){
  float m = fmaxf(fmaxf(a, b), c);
  return m + log2_fast(exp2_fast(a - m) + exp2_fast(b - m) + exp2_fast(c - m));
}

// DPP wave_shr:1  (lane n <- lane n-1; lane 0 <- `old`) : single VALU op
__device__ __forceinline__ float dpp_shr1_f(float oldv, float src){
  return __int_as_float(__builtin_amdgcn_update_dpp(
      __float_as_int(oldv), __float_as_int(src), 0x138, 0xF, 0xF, false));
}
__device__ __forceinline__ int dpp_shr1_i(int oldv, int src){
  return __builtin_amdgcn_update_dpp(oldv, src, 0x138, 0xF, 0xF, false);
}

// async global->LDS: 8448 bytes = 8 x (64 lanes x 16B) + 1 x (64 lanes x 4B)
__device__ __forceinline__ void stage_chunk(const char* gsrc, float* ldst){
  const int lane = threadIdx.x & 63;
  #pragma unroll
  for (int i = 0; i < 8; ++i){
    __builtin_amdgcn_global_load_lds(
      (const __attribute__((address_space(1))) unsigned int*)(gsrc + i*1024 + lane*16),
      (__attribute__((address_space(3))) unsigned int*)((char*)ldst + i*1024),
      16, 0, 0);
  }
  __builtin_amdgcn_global_load_lds(
      (const __attribute__((address_space(1))) unsigned int*)(gsrc + 8192 + lane*4),
      (__attribute__((address_space(3))) unsigned int*)((char*)ldst + 8192),
      4, 0, 0);
}

// ---- Kernel 1: fused softmax + per-b emission-prob stream (linear domain) ----
__global__ __launch_bounds__(256) void em_kernel(const float* __restrict__ acts,
                                                 const int* __restrict__ labels,
                                                 const int* __restrict__ act_lens,
                                                 const int* __restrict__ label_lens,
                                                 float* __restrict__ em){
  const int wid  = threadIdx.x >> 6;
  const int lane = threadIdx.x & 63;
  const int row  = blockIdx.x * 4 + wid;          // row = t*B + b
  const int t = row >> 6;
  const int b = row & (B_DIM - 1);

  __shared__ float sh[4][V_DIM];

  const float2 v = ((const float2*)(acts + (size_t)row * V_DIM))[lane];
  float m = fmaxf(v.x, v.y);
  #pragma unroll
  for (int o = 32; o; o >>= 1) m = fmaxf(m, __shfl_xor(m, o, 64));
  float s = exp2_fast((v.x - m) * INV_LN2) + exp2_fast((v.y - m) * INV_LN2);
  #pragma unroll
  for (int o = 32; o; o >>= 1) s += __shfl_xor(s, o, 64);
  const float d2 = fmaf(m, INV_LN2, log2_fast(s));     // log2 softmax denom

  sh[wid][2 * lane]     = v.x;
  sh[wid][2 * lane + 1] = v.y;

  int masked = (lane < b) ? label_lens[lane] : 0;
  int off = masked;
  #pragma unroll
  for (int o = 1; o < 64; o <<= 1) off += __shfl_xor(off, o, 64);
  const int L = label_lens[b];

  __syncthreads();

  if (t >= act_lens[b]) return;   // rows past act_len are never read by ctc steps
                                  // (safe: the barrier above is already passed)
  const int j0 = 2 * lane, j1 = 2 * lane + 1;
  const int lab0 = (j0 < L) ? labels[off + j0] : 0;
  const int lab1 = (j1 < L) ? labels[off + j1] : 0;
  const float p0 = exp2_fast(fmaf(sh[wid][lab0], INV_LN2, -d2));   // linear probs
  const float p1 = exp2_fast(fmaf(sh[wid][lab1], INV_LN2, -d2));

  float* er = em + ((size_t)b * T_DIM + t) * ROWF;
  ((float2*)er)[lane] = make_float2(p0, p1);
  if (lane == 0) er[128] = exp2_fast(fmaf(sh[wid][0], INV_LN2, -d2));  // blank
}

// ---- Kernel 2: per-batch linear-domain CTC recursion, 1 wave / b -------------
__global__ __launch_bounds__(64) void ctc_lin_kernel(const float* __restrict__ em,
    const int* __restrict__ labels, const int* __restrict__ act_lens,
    const int* __restrict__ label_lens, float* __restrict__ costs)
{
  __shared__ __align__(16) float sbuf[4 * CHUNK_FLOATS];   // 33.8 KB ring (4 bufs)
  __shared__ float A[257];
  __shared__ int   KK[64];

  const int b = blockIdx.x, tid = threadIdx.x;
  const int L = label_lens[b];
  int alen = act_lens[b]; if (alen > T_DIM) alen = T_DIM; if (alen < 1) alen = 1;

  int masked = (tid < b) ? label_lens[tid] : 0;
  int off = masked;
  #pragma unroll
  for (int o = 1; o < 64; o <<= 1) off += __shfl_xor(off, o, 64);

  const int j0 = 2*tid, j1 = 2*tid+1, jm1 = 2*tid-1;
  const int lab0  = (j0 < L) ? labels[off + j0] : 0;
  const int lab1  = (j1 < L) ? labels[off + j1] : 0;
  const int labm1 = (tid == 0) ? -1 : ((jm1 < L) ? labels[off + jm1] : 0);
  const bool skip1 = (lab0 != 0) && (lab0 != labm1);
  const bool skip3 = (lab1 != 0) && (lab1 != lab0);

  // linear-domain alpha; per-thread block exponent K: true = a * 2^K
  float a0 = (tid == 0) ? 1.0f : 0.0f;
  float a1 = 0.0f, a2 = 0.0f, a3 = 0.0f, a4 = 0.0f;
  int K = 0;
  float a3L = 0.0f;        // left neighbor's a3/n3 (in left frame)
  float factor0 = 0.0f;    // 2^(KL-K); 0 on tid 0
  float fac1    = 0.0f;    // factor0 gated by skip1

  const char* em_b = (const char*)(em + (size_t)b * T_DIM * ROWF);

  stage_chunk(em_b + 0*(size_t)CHUNK_BYTES, sbuf);
  stage_chunk(em_b + 1*(size_t)CHUNK_BYTES, sbuf + CHUNK_FLOATS);
  stage_chunk(em_b + 2*(size_t)CHUNK_BYTES, sbuf + 2*CHUNK_FLOATS);

  // rescale window boundary (every 4 steps): normalize thread max to ~2^30
  auto boundary = [&](){
    float m = fmaxf(fmaxf(fmaxf(a0, a1), fmaxf(a2, a3)), a4);
    int e; (void)frexpf(m, &e);                 // m==0 -> e=0
    const float sc = ldexpf(1.0f, 30 - e);
    a0 *= sc; a1 *= sc; a2 *= sc; a3 *= sc; a4 *= sc;
    K += e - 30;
    const bool dead = (m == 0.0f);
    const int KL = dpp_shr1_i(K, K);            // lane0 keeps own K
    K = dead ? KL : K;                          // adopt left frame when dead
    int sh = KL - K;                            // 0 when adopted / lane0
    sh = (sh > 90) ? 90 : sh;                   // overflow safety (import dominates)
    const float f = ldexpf(1.0f, sh);
    factor0 = (tid == 0) ? 0.0f : f;
    fac1    = skip1 ? factor0 : 0.0f;
    a3L = dpp_shr1_f(0.0f, a3);                 // refresh post-rescale
  };

  auto step = [&](float p0, float p1, float pb){
    const float imp = a3L * factor0;            // alpha[4tid-1] in our frame
    const float c1  = a3L * fac1;
    const float c3  = skip3 ? a1 : 0.0f;
    const float n0 = pb * (a0 + imp);
    const float n1 = p0 * (a1 + a0 + c1);
    const float n2 = pb * (a2 + a1);
    const float n3 = p1 * (a3 + a2 + c3);
    const float n4 = pb * (a4 + a3);
    a3L = dpp_shr1_f(0.0f, n3);                 // VALU DPP, ~4 cy
    a0 = n0; a1 = n1; a2 = n2; a3 = n3; a4 = n4;
  };

  const int nfull = alen >> 4;
  const int rem   = alen & 15;

  for (int c = 0; c < nfull; ++c){
    float* cur = sbuf + (size_t)(c & 3) * CHUNK_FLOATS;
    if (c + 3 < NCHUNK){
      stage_chunk(em_b + (size_t)(c + 3) * CHUNK_BYTES,
                  sbuf + (size_t)((c + 3) & 3) * CHUNK_FLOATS);
      asm volatile("s_waitcnt vmcnt(27)" ::: "memory");   // chunk c landed; 3 in flight
    } else {
      asm volatile("s_waitcnt vmcnt(0)" ::: "memory");
    }
    // hoist all 16 rows to registers: ds latency paid once per chunk
    float2 P[16]; float PB[16];
    #pragma unroll
    for (int k = 0; k < 16; ++k){
      const float* r = cur + k * ROWF;
      P[k]  = *(const float2*)(r + 2*tid);
      PB[k] = r[128];
    }
    #pragma unroll
    for (int w = 0; w < 4; ++w){
      boundary();
      #pragma unroll
      for (int k = 0; k < 4; ++k) step(P[w*4+k].x, P[w*4+k].y, PB[w*4+k]);
    }
  }
  if (rem){
    asm volatile("s_waitcnt vmcnt(0)" ::: "memory");
    float* cur = sbuf + (size_t)(nfull & 3) * CHUNK_FLOATS;
    float2 P[16]; float PB[16];
    #pragma unroll
    for (int k = 0; k < 16; ++k){
      const float* r = cur + k * ROWF;
      P[k]  = *(const float2*)(r + 2*tid);
      PB[k] = r[128];
    }
    #pragma unroll
    for (int w = 0; w < 4; ++w){
      if (w*4 < rem){                 // wave-uniform
        boundary();
        #pragma unroll
        for (int k = 0; k < 4; ++k){
          if (w*4 + k < rem) step(P[w*4+k].x, P[w*4+k].y, PB[w*4+k]);
        }
      }
    }
  }

  A[4*tid] = a0; A[4*tid+1] = a1; A[4*tid+2] = a2; A[4*tid+3] = a3;
  if (tid == 63) A[256] = a4;
  KK[tid] = K;
  __syncthreads();
  if (tid == 0){
    const int sL = 2 * L;
    int ia = sL >> 2;       if (ia > 63) ia = 63;
    int ib = (sL - 1) >> 2; if (ib > 63) ib = 63;
    const float la = log2_fast(A[sL])     + (float)KK[ia];
    const float lb = log2_fast(A[sL - 1]) + (float)KK[ib];
    costs[b] = -LN2F * lae2_log2(la, lb);
  }
}

// ---- Kernel 3: deterministic sum ------------------------------------------
__global__ __launch_bounds__(64) void sum_kernel(const float* __restrict__ costs,
                                                 float* __restrict__ out){
  float v = costs[threadIdx.x];
  #pragma unroll
  for (int o = 32; o; o >>= 1) v += __shfl_xor(v, o, 64);
  if (threadIdx.x == 0) out[0] = v;
}

// ---- Fallback path (proven round-1, if ws too small) -----------------------
__global__ __launch_bounds__(256) void lse_kernel(const float* __restrict__ acts,
                                                  float* __restrict__ denom){
  int row  = (blockIdx.x * 256 + threadIdx.x) >> 6;
  int lane = threadIdx.x & 63;
  if (row >= T_DIM * B_DIM) return;
  const float2 v = ((const float2*)(acts + (size_t)row * V_DIM))[lane];
  float m = fmaxf(v.x, v.y);
  #pragma unroll
  for (int o = 32; o; o >>= 1) m = fmaxf(m, __shfl_xor(m, o, 64));
  float s = exp2_fast((v.x - m) * INV_LN2) + exp2_fast((v.y - m) * INV_LN2);
  #pragma unroll
  for (int o = 32; o; o >>= 1) s += __shfl_xor(s, o, 64);
  if (lane == 0) denom[row] = fmaf(m, INV_LN2, log2_fast(s));
}

__global__ __launch_bounds__(64) void ctc_gather_kernel(
    const float* __restrict__ acts, const int* __restrict__ labels,
    const int* __restrict__ act_lens, const int* __restrict__ label_lens,
    const float* __restrict__ denom, float* __restrict__ costs){
  const int b = blockIdx.x, tid = threadIdx.x;
  const int L = label_lens[b];
  int alen = act_lens[b]; if (alen > T_DIM) alen = T_DIM;
  int masked = (tid < b) ? label_lens[tid] : 0;
  int off = masked;
  #pragma unroll
  for (int o = 1; o < 64; o <<= 1) off += __shfl_xor(off, o, 64);
  const int j0 = 2*tid, j1 = 2*tid+1, jm1 = 2*tid-1;
  const int lab0  = (j0 < L) ? labels[off + j0] : 0;
  const int lab1  = (j1 < L) ? labels[off + j1] : 0;
  const int labm1 = (tid == 0) ? -1 : ((jm1 < L) ? labels[off + jm1] : 0);
  const bool skip1 = (lab0 != 0) && (lab0 != labm1);
  const bool skip3 = (lab1 != 0) && (lab1 != lab0);
  float a0 = (tid == 0) ? 0.0f : NEG2;
  float a1 = NEG2, a2 = NEG2, a3 = NEG2, a4 = NEG2, a3L = NEG2;
  const float* actsB = acts + (size_t)b * V_DIM;
  for (int t = 0; t < alen; ++t){
    const float* base = actsB + (size_t)t * (B_DIM * V_DIM);
    const float d  = denom[t * B_DIM + b];
    const float eb = fmaf(base[0],    INV_LN2, -d);
    const float e0 = fmaf(base[lab0], INV_LN2, -d);
    const float e1 = fmaf(base[lab1], INV_LN2, -d);
    const float c1 = skip1 ? a3L : NEG2;
    const float c3 = skip3 ? a1  : NEG2;
    const float n0 = eb + lae2_log2(a0, a3L);
    const float n1 = e0 + lae3_log2(a1, a0, c1);
    const float n2 = eb + lae2_log2(a2, a1);
    const float n3 = e1 + lae3_log2(a3, a2, c3);
    const float n4 = eb + lae2_log2(a4, a3);
    float nl = __shfl_up(n3, 1, 64);
    a3L = (tid == 0) ? NEG2 : nl;
    a0 = n0; a1 = n1; a2 = n2; a3 = n3; a4 = n4;
  }
  __shared__ float A[257];
  A[4*tid] = a0; A[4*tid+1] = a1; A[4*tid+2] = a2; A[4*tid+3] = a3;
  if (tid == 63) A[256] = a4;
  __syncthreads();
  if (tid == 0){
    const int sL = 2 * L;
    costs[b] = -LN2F * lae2_log2(A[sL], A[sL - 1]);
  }
}

extern "C" void kernel_launch(void* const* d_in, const int* in_sizes, int n_in,
                              void* d_out, int out_size, void* d_ws, size_t ws_size,
                              hipStream_t stream){
  const float* acts       = (const float*)d_in[0];
  const int*   labels     = (const int*)d_in[1];
  const int*   act_lens   = (const int*)d_in[2];
  const int*   label_lens = (const int*)d_in[3];
  float* out = (float*)d_out;

  const size_t em_floats = (size_t)B_DIM * T_DIM * ROWF;
  const size_t need = (em_floats + 64) * sizeof(float);

  if (ws_size >= need){
    float* em    = (float*)d_ws;
    float* costs = em + em_floats;
    em_kernel<<<(T_DIM * B_DIM) / 4, 256, 0, stream>>>(acts, labels, act_lens, label_lens, em);
    ctc_lin_kernel<<<B_DIM, 64, 0, stream>>>(em, labels, act_lens, label_lens, costs);
    sum_kernel<<<1, 64, 0, stream>>>(costs, out);
  } else {
    float* denom = (float*)d_ws;
    float* costs = denom + (size_t)T_DIM * B_DIM;
    lse_kernel<<<(T_DIM * B_DIM) / 4, 256, 0, stream>>>(acts, denom);
    ctc_gather_kernel<<<B_DIM, 64, 0, stream>>>(acts, labels, act_lens, label_lens, denom, costs);
    sum_kernel<<<1, 64, 0, stream>>>(costs, out);
  }
}